// Round 1
// baseline (81.935 us; speedup 1.0000x reference)
//
#include <hip/hip_runtime.h>

#define GAMMA_F 267.52f

// Fully fused: cos/sin + 7-point Laplacian + phase combine + mask + scale,
// plus the lfs Laplacian, one pass, both outputs.
// Layout (B,C,H,W,D) = (2,1,256,256,128), D contiguous.
// Thread: 4 consecutive D elements (one float4). Block: 32 quads x 8 w-rows.
__global__ __launch_bounds__(256) void lot_fused_kernel(
    const float* __restrict__ phi,
    const float* __restrict__ lfs,
    const float* __restrict__ mask,
    const float* __restrict__ TE,
    const float* __restrict__ B0,
    const float* __restrict__ kern,
    float* __restrict__ out_b,
    float* __restrict__ out_d)
{
    constexpr int H = 256, W = 256, D = 128;
    constexpr long long sW = D;
    constexpr long long sH = (long long)W * D;
    constexpr long long sB = (long long)H * W * D;

    const int tid  = threadIdx.x;
    const int q    = tid & 31;        // which float4 along D
    const int wrow = tid >> 5;        // 0..7
    const int w    = blockIdx.x * 8 + wrow;
    const int h    = blockIdx.y;
    const int b    = blockIdx.z;
    const int d0   = q * 4;

    const long long base = (long long)b * sB + (long long)h * sH
                         + (long long)w * sW + d0;

    // Boundary slices along h and w are zeroed outputs.
    if (h == 0 || h == H - 1 || w == 0 || w == W - 1) {
        *(float4*)(out_b + base) = make_float4(0.f, 0.f, 0.f, 0.f);
        *(float4*)(out_d + base) = make_float4(0.f, 0.f, 0.f, 0.f);
        return;
    }

    // 7-point Laplacian coefficients from the 3x3x3 kernel input.
    // k flat index = kd*9 + kh*3 + kw over spatial dims (H, W, D) of x.
    const float kH = kern[4];    // k[0,1,1] -> h +/- 1
    const float kW = kern[10];   // k[1,0,1] -> w +/- 1
    const float kD = kern[12];   // k[1,1,0] -> d +/- 1
    const float kC = kern[13];   // k[1,1,1] -> center
    const float scale = -1.0f / (B0[0] * TE[b] * GAMMA_F);

    // ---- phi neighborhood ----
    const float4 pc  = *(const float4*)(phi + base);
    const float  pm  = (d0 > 0)     ? phi[base - 1] : 0.f;  // only needed when d>0
    const float  pp  = (d0 + 4 < D) ? phi[base + 4] : 0.f;  // only needed when d<D-1
    const float4 pw0 = *(const float4*)(phi + base - sW);
    const float4 pw1 = *(const float4*)(phi + base + sW);
    const float4 ph0 = *(const float4*)(phi + base - sH);
    const float4 ph1 = *(const float4*)(phi + base + sH);

    float ce[6], se[6];
    {
        const float x[6] = { pm, pc.x, pc.y, pc.z, pc.w, pp };
        #pragma unroll
        for (int i = 0; i < 6; ++i) { se[i] = __sinf(x[i]); ce[i] = __cosf(x[i]); }
    }
    float cw0[4], sw0[4], cw1[4], sw1[4], ch0[4], sh0[4], ch1[4], sh1[4];
    {
        const float xw0[4] = { pw0.x, pw0.y, pw0.z, pw0.w };
        const float xw1[4] = { pw1.x, pw1.y, pw1.z, pw1.w };
        const float xh0[4] = { ph0.x, ph0.y, ph0.z, ph0.w };
        const float xh1[4] = { ph1.x, ph1.y, ph1.z, ph1.w };
        #pragma unroll
        for (int i = 0; i < 4; ++i) {
            sw0[i] = __sinf(xw0[i]); cw0[i] = __cosf(xw0[i]);
            sw1[i] = __sinf(xw1[i]); cw1[i] = __cosf(xw1[i]);
            sh0[i] = __sinf(xh0[i]); ch0[i] = __cosf(xh0[i]);
            sh1[i] = __sinf(xh1[i]); ch1[i] = __cosf(xh1[i]);
        }
    }

    // ---- lfs neighborhood ----
    const float4 lc  = *(const float4*)(lfs + base);
    const float  lm  = (d0 > 0)     ? lfs[base - 1] : 0.f;
    const float  lp  = (d0 + 4 < D) ? lfs[base + 4] : 0.f;
    const float4 lw0 = *(const float4*)(lfs + base - sW);
    const float4 lw1 = *(const float4*)(lfs + base + sW);
    const float4 lh0 = *(const float4*)(lfs + base - sH);
    const float4 lh1 = *(const float4*)(lfs + base + sH);
    const float le[6]  = { lm, lc.x, lc.y, lc.z, lc.w, lp };
    const float lwa[4] = { lw0.x, lw0.y, lw0.z, lw0.w };
    const float lwb[4] = { lw1.x, lw1.y, lw1.z, lw1.w };
    const float lha[4] = { lh0.x, lh0.y, lh0.z, lh0.w };
    const float lhb[4] = { lh1.x, lh1.y, lh1.z, lh1.w };

    const float4 mk4 = *(const float4*)(mask + base);
    const float mk[4] = { mk4.x, mk4.y, mk4.z, mk4.w };

    float ob[4], od[4];
    #pragma unroll
    for (int j = 0; j < 4; ++j) {
        const float a_r = kC*ce[j+1] + kD*(ce[j]+ce[j+2])
                        + kW*(cw0[j]+cw1[j]) + kH*(ch0[j]+ch1[j]);
        const float a_i = kC*se[j+1] + kD*(se[j]+se[j+2])
                        + kW*(sw0[j]+sw1[j]) + kH*(sh0[j]+sh1[j]);
        float bi = (a_i*ce[j+1] - a_r*se[j+1]) * mk[j] * scale;

        const float lap = kC*le[j+1] + kD*(le[j]+le[j+2])
                        + kW*(lwa[j]+lwb[j]) + kH*(lha[j]+lhb[j]);
        float di = lap * mk[j];

        const int d = d0 + j;
        if (d == 0 || d == D - 1) { bi = 0.f; di = 0.f; }
        ob[j] = bi; od[j] = di;
    }

    *(float4*)(out_b + base) = make_float4(ob[0], ob[1], ob[2], ob[3]);
    *(float4*)(out_d + base) = make_float4(od[0], od[1], od[2], od[3]);
}

extern "C" void kernel_launch(void* const* d_in, const int* in_sizes, int n_in,
                              void* d_out, int out_size, void* d_ws, size_t ws_size,
                              hipStream_t stream) {
    const float* phi  = (const float*)d_in[0];
    const float* lfs  = (const float*)d_in[1];
    const float* mask = (const float*)d_in[2];
    const float* TE   = (const float*)d_in[3];
    const float* B0   = (const float*)d_in[4];
    const float* kern = (const float*)d_in[5];

    float* out_b = (float*)d_out;                       // b_i, 2*1*256*256*128
    float* out_d = out_b + (long long)2 * 256 * 256 * 128;  // d_i follows

    dim3 grid(256 / 8, 256, 2);   // (w tiles, h, b)
    dim3 block(256);
    hipLaunchKernelGGL(lot_fused_kernel, grid, block, 0, stream,
                       phi, lfs, mask, TE, B0, kern, out_b, out_d);
}

// Round 2
// 74.144 us; speedup vs baseline: 1.1051x; 1.1051x over previous
//
#include <hip/hip_runtime.h>

#define GAMMA_F 267.52f

typedef float v4f __attribute__((ext_vector_type(4)));

constexpr int H = 256, W = 256, D = 128;
constexpr int HS = 8;                      // h-rows marched per thread
constexpr long long sW = D;
constexpr long long sH = (long long)W * D;
constexpr long long sB = (long long)H * (long long)W * D;

// Thread: fixed (b, w, d-quad), marches HS rows along h.
// Registers hold 3 rolling "lines" (d-quad + d-halo = 6 values) of
// sincos(phi) and raw lfs; each step loads only ONE new line + the
// w+/-1 row-h neighbors.
__global__ __launch_bounds__(256) void lot_fused_hmarch(
    const float* __restrict__ phi,
    const float* __restrict__ lfs,
    const float* __restrict__ mask,
    const float* __restrict__ TE,
    const float* __restrict__ B0,
    const float* __restrict__ kern,
    float* __restrict__ out_b,
    float* __restrict__ out_d)
{
    const int tid = threadIdx.x;
    const int q   = tid & 31;          // d-quad index
    const int wr  = tid >> 5;          // 0..7
    const int w   = blockIdx.x * 8 + wr;
    const int h0  = blockIdx.y * HS;
    const int b   = blockIdx.z;
    const int d0  = q * 4;

    const long long colBase = (long long)b * sB + (long long)w * sW + d0;

    // whole w-boundary column is zeros
    if (w == 0 || w == W - 1) {
        const v4f z = {0.f, 0.f, 0.f, 0.f};
        #pragma unroll
        for (int i = 0; i < HS; ++i) {
            const long long r = colBase + (long long)(h0 + i) * sH;
            __builtin_nontemporal_store(z, (v4f*)(out_b + r));
            __builtin_nontemporal_store(z, (v4f*)(out_d + r));
        }
        return;
    }

    // 7-point coefficients (flat 3x3x3: kd*9+kh*3+kw)
    const float kHc = kern[4];    // first spatial dim +/-1
    const float kWc = kern[10];   // second spatial dim +/-1
    const float kDc = kern[12];   // third (contiguous) dim +/-1
    const float kCc = kern[13];   // center
    const float scale = -1.0f / (B0[0] * TE[b] * GAMMA_F);

    float Ps[3][6], Pc[3][6], Fl[3][6];   // rolling sin/cos/lfs lines

    #define LOAD_LINE(hh, SLOT)                                              \
    do {                                                                     \
        const int _h = (hh);                                                 \
        if (_h >= 0 && _h < H) {                                             \
            const long long _r = colBase + (long long)_h * sH;               \
            const v4f _p = *(const v4f*)(phi + _r);                          \
            const v4f _l = *(const v4f*)(lfs + _r);                          \
            float _t[6];                                                     \
            _t[1] = _p.x; _t[2] = _p.y; _t[3] = _p.z; _t[4] = _p.w;          \
            _t[0] = (d0 > 0)     ? phi[_r - 1] : 0.f;                        \
            _t[5] = (d0 + 4 < D) ? phi[_r + 4] : 0.f;                        \
            Fl[SLOT][1] = _l.x; Fl[SLOT][2] = _l.y;                          \
            Fl[SLOT][3] = _l.z; Fl[SLOT][4] = _l.w;                          \
            Fl[SLOT][0] = (d0 > 0)     ? lfs[_r - 1] : 0.f;                  \
            Fl[SLOT][5] = (d0 + 4 < D) ? lfs[_r + 4] : 0.f;                  \
            _Pragma("unroll")                                                \
            for (int _j = 0; _j < 6; ++_j) {                                 \
                Ps[SLOT][_j] = __sinf(_t[_j]);                               \
                Pc[SLOT][_j] = __cosf(_t[_j]);                               \
            }                                                                \
        } else {                                                             \
            _Pragma("unroll")                                                \
            for (int _j = 0; _j < 6; ++_j) {                                 \
                Ps[SLOT][_j] = 0.f; Pc[SLOT][_j] = 0.f; Fl[SLOT][_j] = 0.f;  \
            }                                                                \
        }                                                                    \
    } while (0)

    // prologue: row (h0-1) -> slot 0, row h0 -> slot 1
    LOAD_LINE(h0 - 1, 0);
    LOAD_LINE(h0,     1);

    #pragma unroll
    for (int i = 0; i < HS; ++i) {
        const int h  = h0 + i;
        const int sm = i % 3;            // row h-1
        const int sc = (i + 1) % 3;      // row h
        const int sp = (i + 2) % 3;      // row h+1
        LOAD_LINE(h + 1, sp);            // issue next-line loads first

        const long long r = colBase + (long long)h * sH;
        if (h == 0 || h == H - 1) {
            const v4f z = {0.f, 0.f, 0.f, 0.f};
            __builtin_nontemporal_store(z, (v4f*)(out_b + r));
            __builtin_nontemporal_store(z, (v4f*)(out_d + r));
        } else {
            const v4f pw0 = *(const v4f*)(phi + r - sW);
            const v4f pw1 = *(const v4f*)(phi + r + sW);
            const v4f lw0 = *(const v4f*)(lfs + r - sW);
            const v4f lw1 = *(const v4f*)(lfs + r + sW);
            const v4f mk  = *(const v4f*)(mask + r);

            float sw0[4], cw0[4], sw1[4], cw1[4];
            {
                const float x0[4] = {pw0.x, pw0.y, pw0.z, pw0.w};
                const float x1[4] = {pw1.x, pw1.y, pw1.z, pw1.w};
                #pragma unroll
                for (int j = 0; j < 4; ++j) {
                    sw0[j] = __sinf(x0[j]); cw0[j] = __cosf(x0[j]);
                    sw1[j] = __sinf(x1[j]); cw1[j] = __cosf(x1[j]);
                }
            }
            const float lwv0[4] = {lw0.x, lw0.y, lw0.z, lw0.w};
            const float lwv1[4] = {lw1.x, lw1.y, lw1.z, lw1.w};
            const float mkv[4]  = {mk.x, mk.y, mk.z, mk.w};

            float ob[4], od[4];
            #pragma unroll
            for (int j = 0; j < 4; ++j) {
                const float se = Ps[sc][j + 1], ce = Pc[sc][j + 1];
                const float a_r = kCc * ce
                                + kDc * (Pc[sc][j] + Pc[sc][j + 2])
                                + kWc * (cw0[j] + cw1[j])
                                + kHc * (Pc[sm][j + 1] + Pc[sp][j + 1]);
                const float a_i = kCc * se
                                + kDc * (Ps[sc][j] + Ps[sc][j + 2])
                                + kWc * (sw0[j] + sw1[j])
                                + kHc * (Ps[sm][j + 1] + Ps[sp][j + 1]);
                float bi = (a_i * ce - a_r * se) * mkv[j] * scale;

                const float lap = kCc * Fl[sc][j + 1]
                                + kDc * (Fl[sc][j] + Fl[sc][j + 2])
                                + kWc * (lwv0[j] + lwv1[j])
                                + kHc * (Fl[sm][j + 1] + Fl[sp][j + 1]);
                float di = lap * mkv[j];

                const int d = d0 + j;
                if (d == 0 || d == D - 1) { bi = 0.f; di = 0.f; }
                ob[j] = bi; od[j] = di;
            }
            const v4f vb = {ob[0], ob[1], ob[2], ob[3]};
            const v4f vd = {od[0], od[1], od[2], od[3]};
            __builtin_nontemporal_store(vb, (v4f*)(out_b + r));
            __builtin_nontemporal_store(vd, (v4f*)(out_d + r));
        }
    }
    #undef LOAD_LINE
}

extern "C" void kernel_launch(void* const* d_in, const int* in_sizes, int n_in,
                              void* d_out, int out_size, void* d_ws, size_t ws_size,
                              hipStream_t stream) {
    const float* phi  = (const float*)d_in[0];
    const float* lfs  = (const float*)d_in[1];
    const float* mask = (const float*)d_in[2];
    const float* TE   = (const float*)d_in[3];
    const float* B0   = (const float*)d_in[4];
    const float* kern = (const float*)d_in[5];

    float* out_b = (float*)d_out;
    float* out_d = out_b + sB * 2;   // B=2, C=1

    dim3 grid(W / 8, H / HS, 2);
    dim3 block(256);
    hipLaunchKernelGGL(lot_fused_hmarch, grid, block, 0, stream,
                       phi, lfs, mask, TE, B0, kern, out_b, out_d);
}

// Round 3
// 66.940 us; speedup vs baseline: 1.2240x; 1.1076x over previous
//
#include <hip/hip_runtime.h>

#define GAMMA_F 267.52f
typedef float v4f __attribute__((ext_vector_type(4)));

constexpr int H = 256, W = 256, D = 128;
constexpr int WT = 8;          // w-lines per block
constexpr int HS = 16;         // h-rows marched per block
constexpr int LW = WT + 2;     // 10 lines incl. w-halo
constexpr int LD = D + 4;      // 132 floats: LDS idx = d+1 (d=-1..128), padded
constexpr long long sW = D;
constexpr long long sH = (long long)W * D;
constexpr long long sB = (long long)H * (long long)W * D;

// Block: 256 threads = 32 d-quads x 8 w-lines, marches HS h-rows.
// sincos(phi) computed ONCE per element into a 3-row LDS ring; the 7-point
// stencil reads d/w/h neighbors from LDS. lfs rolls in a register ring.
// All out-of-volume halo slots hold garbage -- only ever read by outputs
// that are forced to zero (conv zero-padding + boundary-slice zeroing).
__global__ __launch_bounds__(256) void lot_lds_march(
    const float* __restrict__ phi,
    const float* __restrict__ lfs,
    const float* __restrict__ mask,
    const float* __restrict__ TE,
    const float* __restrict__ B0,
    const float* __restrict__ kern,
    float* __restrict__ out_b,
    float* __restrict__ out_d)
{
    __shared__ float Ssin[3][LW][LD];
    __shared__ float Scos[3][LW][LD];

    const int tid = threadIdx.x;
    const int q   = tid & 31;
    const int wr  = tid >> 5;
    const int w0  = blockIdx.x * WT;
    const int h0  = blockIdx.y * HS;
    const int b   = blockIdx.z;
    const int w   = w0 + wr;
    const int d0  = q * 4;
    const int lwc = wr + 1;         // this thread's LDS w-line

    const long long colBase = (long long)b * sB + (long long)w * sW + d0;

    const float kHc = kern[4];      // h +/- 1
    const float kWc = kern[10];     // w +/- 1
    const float kDc = kern[12];     // d +/- 1
    const float kCc = kern[13];     // center
    const float scale = -1.0f / (B0[0] * TE[b] * GAMMA_F);

    // w-halo duty: wr==0 also loads line w0-1, wr==7 loads line w0+8
    const bool haloLo  = (wr == 0)      && (w0 > 0);
    const bool haloHi  = (wr == WT - 1) && (w0 + WT < W);
    const bool hasHalo = haloLo || haloHi;
    const long long haloOff = haloLo ? -sW : sW;
    const int  haloLw  = haloLo ? 0 : (LW - 1);

    #define PHI_LOAD(hh, PREG, PHREG)                                        \
    do {                                                                     \
        const int _h = (hh);                                                 \
        if (_h >= 0 && _h < H) {                                             \
            const long long _r = colBase + (long long)_h * sH;               \
            PREG = *(const v4f*)(phi + _r);                                  \
            if (hasHalo) PHREG = *(const v4f*)(phi + _r + haloOff);          \
        }                                                                    \
    } while (0)

    #define PHI_STORE(SLOT, PREG, PHREG)                                     \
    do {                                                                     \
        const int _s = (SLOT);                                               \
        Ssin[_s][lwc][d0 + 1] = __sinf(PREG.x);                              \
        Ssin[_s][lwc][d0 + 2] = __sinf(PREG.y);                              \
        Ssin[_s][lwc][d0 + 3] = __sinf(PREG.z);                              \
        Ssin[_s][lwc][d0 + 4] = __sinf(PREG.w);                              \
        Scos[_s][lwc][d0 + 1] = __cosf(PREG.x);                              \
        Scos[_s][lwc][d0 + 2] = __cosf(PREG.y);                              \
        Scos[_s][lwc][d0 + 3] = __cosf(PREG.z);                              \
        Scos[_s][lwc][d0 + 4] = __cosf(PREG.w);                              \
        if (hasHalo) {                                                       \
            Ssin[_s][haloLw][d0 + 1] = __sinf(PHREG.x);                      \
            Ssin[_s][haloLw][d0 + 2] = __sinf(PHREG.y);                      \
            Ssin[_s][haloLw][d0 + 3] = __sinf(PHREG.z);                      \
            Ssin[_s][haloLw][d0 + 4] = __sinf(PHREG.w);                      \
            Scos[_s][haloLw][d0 + 1] = __cosf(PHREG.x);                      \
            Scos[_s][haloLw][d0 + 2] = __cosf(PHREG.y);                      \
            Scos[_s][haloLw][d0 + 3] = __cosf(PHREG.z);                      \
            Scos[_s][haloLw][d0 + 4] = __cosf(PHREG.w);                      \
        }                                                                    \
    } while (0)

    #define LFS_LOAD(hh, F)                                                  \
    do {                                                                     \
        const int _h = (hh);                                                 \
        if (_h >= 0 && _h < H) {                                             \
            const long long _r = colBase + (long long)_h * sH;               \
            const v4f _l = *(const v4f*)(lfs + _r);                          \
            F[1] = _l.x; F[2] = _l.y; F[3] = _l.z; F[4] = _l.w;              \
            F[0] = (d0 > 0)     ? lfs[_r - 1] : 0.f;                         \
            F[5] = (d0 + 4 < D) ? lfs[_r + 4] : 0.f;                         \
        } else {                                                             \
            _Pragma("unroll")                                                \
            for (int _j = 0; _j < 6; ++_j) F[_j] = 0.f;                      \
        }                                                                    \
    } while (0)

    float FlA[6], FlB[6], FlC[6];
    v4f pT = {0.f, 0.f, 0.f, 0.f}, pTH = {0.f, 0.f, 0.f, 0.f};

    // prologue: rows h0-1 -> slot0, h0 -> slot1; prefetch row h0+1 to regs
    PHI_LOAD(h0 - 1, pT, pTH);
    PHI_STORE(0, pT, pTH);
    PHI_LOAD(h0, pT, pTH);
    PHI_STORE(1, pT, pTH);
    LFS_LOAD(h0 - 1, FlA);
    LFS_LOAD(h0,     FlB);
    v4f pN = pT, pNH = pTH;
    PHI_LOAD(h0 + 1, pN, pNH);

    int sm = 0, sc = 1, sp = 2;

    for (int i = 0; i < HS; ++i) {
        const int h = h0 + i;

        PHI_STORE(sp, pN, pNH);      // row h+1: trans + LDS write
        LFS_LOAD(h + 1, FlC);
        __syncthreads();             // ring row ready

        // prefetch phi row h+2 during compute (hides HBM latency)
        v4f pN2 = pN, pN2H = pNH;
        PHI_LOAD(h + 2, pN2, pN2H);

        const long long r = colBase + (long long)h * sH;
        if (h == 0 || h == H - 1 || w == 0 || w == W - 1) {
            const v4f z = {0.f, 0.f, 0.f, 0.f};
            __builtin_nontemporal_store(z, (v4f*)(out_b + r));
            __builtin_nontemporal_store(z, (v4f*)(out_d + r));
        } else {
            const v4f lw0 = *(const v4f*)(lfs + r - sW);
            const v4f lw1 = *(const v4f*)(lfs + r + sW);
            const v4f mk  = *(const v4f*)(mask + r);
            const float lwv0[4] = {lw0.x, lw0.y, lw0.z, lw0.w};
            const float lwv1[4] = {lw1.x, lw1.y, lw1.z, lw1.w};
            const float mkv[4]  = {mk.x, mk.y, mk.z, mk.w};

            float ob[4], od[4];
            #pragma unroll
            for (int j = 0; j < 4; ++j) {
                const int di = d0 + 1 + j;
                const float se = Ssin[sc][lwc][di];
                const float ce = Scos[sc][lwc][di];
                const float a_r = kCc * ce
                    + kDc * (Scos[sc][lwc][di - 1] + Scos[sc][lwc][di + 1])
                    + kWc * (Scos[sc][lwc - 1][di] + Scos[sc][lwc + 1][di])
                    + kHc * (Scos[sm][lwc][di]     + Scos[sp][lwc][di]);
                const float a_i = kCc * se
                    + kDc * (Ssin[sc][lwc][di - 1] + Ssin[sc][lwc][di + 1])
                    + kWc * (Ssin[sc][lwc - 1][di] + Ssin[sc][lwc + 1][di])
                    + kHc * (Ssin[sm][lwc][di]     + Ssin[sp][lwc][di]);
                float bi = (a_i * ce - a_r * se) * mkv[j] * scale;

                const float lap = kCc * FlB[j + 1]
                    + kDc * (FlB[j] + FlB[j + 2])
                    + kWc * (lwv0[j] + lwv1[j])
                    + kHc * (FlA[j + 1] + FlC[j + 1]);
                float dv = lap * mkv[j];

                const int d = d0 + j;
                if (d == 0 || d == D - 1) { bi = 0.f; dv = 0.f; }
                ob[j] = bi; od[j] = dv;
            }
            const v4f vb = {ob[0], ob[1], ob[2], ob[3]};
            const v4f vd = {od[0], od[1], od[2], od[3]};
            __builtin_nontemporal_store(vb, (v4f*)(out_b + r));
            __builtin_nontemporal_store(vd, (v4f*)(out_d + r));
        }

        // rotate register ring + LDS ring
        pN = pN2; pNH = pN2H;
        #pragma unroll
        for (int j2 = 0; j2 < 6; ++j2) { FlA[j2] = FlB[j2]; FlB[j2] = FlC[j2]; }
        const int t = sm; sm = sc; sc = sp; sp = t;

        __syncthreads();             // compute done before next overwrite of sp
    }

    #undef PHI_LOAD
    #undef PHI_STORE
    #undef LFS_LOAD
}

extern "C" void kernel_launch(void* const* d_in, const int* in_sizes, int n_in,
                              void* d_out, int out_size, void* d_ws, size_t ws_size,
                              hipStream_t stream) {
    const float* phi  = (const float*)d_in[0];
    const float* lfs  = (const float*)d_in[1];
    const float* mask = (const float*)d_in[2];
    const float* TE   = (const float*)d_in[3];
    const float* B0   = (const float*)d_in[4];
    const float* kern = (const float*)d_in[5];

    float* out_b = (float*)d_out;
    float* out_d = out_b + sB * 2;   // B=2, C=1

    dim3 grid(W / WT, H / HS, 2);
    dim3 block(256);
    hipLaunchKernelGGL(lot_lds_march, grid, block, 0, stream,
                       phi, lfs, mask, TE, B0, kern, out_b, out_d);
}

// Round 4
// 65.897 us; speedup vs baseline: 1.2434x; 1.0158x over previous
//
#include <hip/hip_runtime.h>

#define GAMMA_F 267.52f
typedef float v4f __attribute__((ext_vector_type(4)));

constexpr int H = 256, W = 256, D = 128;
constexpr int WT = 8;          // w-lines per block
constexpr int HS = 16;         // h-rows marched per block
constexpr int LW = WT + 2;     // w-lines incl. halo
constexpr long long sW = D;
constexpr long long sH = (long long)W * D;
constexpr long long sB = (long long)H * (long long)W * D;

// Block: 256 threads = 32 d-quads x 8 w-lines, marching HS h-rows.
// sincos(phi) computed once per element, stored to a 3-row LDS ring as
// ALIGNED b128 quads; stencil w/h taps are aligned b128 reads (same d-range
// as output), d+/-1 taps come from registers via 2-lane shuffles.
// lfs: register 6-line ring + global w+/-1 quads (L1/L2 hits).
__global__ __launch_bounds__(256, 4) void lot_lds_v2(
    const float* __restrict__ phi,
    const float* __restrict__ lfs,
    const float* __restrict__ mask,
    const float* __restrict__ TE,
    const float* __restrict__ B0,
    const float* __restrict__ kern,
    float* __restrict__ out_b,
    float* __restrict__ out_d)
{
    __shared__ float Ssin[3][LW][D];
    __shared__ float Scos[3][LW][D];

    const int tid = threadIdx.x;
    const int q   = tid & 31;
    const int wr  = tid >> 5;
    const int w0  = blockIdx.x * WT;
    const int h0  = blockIdx.y * HS;
    const int b   = blockIdx.z;
    const int w   = w0 + wr;
    const int d0  = q * 4;
    const int lwc = wr + 1;

    const long long colBase = (long long)b * sB + (long long)w * sW + d0;

    const float kHc = kern[4];      // h +/- 1
    const float kWc = kern[10];     // w +/- 1
    const float kDc = kern[12];     // d +/- 1
    const float kCc = kern[13];     // center
    const float scale = -1.0f / (B0[0] * TE[b] * GAMMA_F);

    const bool haloLo  = (wr == 0)      && (w0 > 0);
    const bool haloHi  = (wr == WT - 1) && (w0 + WT < W);
    const bool hasHalo = haloLo || haloHi;
    const long long haloOff = haloLo ? -sW : sW;
    const int  haloLw  = haloLo ? 0 : (LW - 1);

    // guarded phi quad load (+ w-halo quad for duty threads)
    #define PHI_LOAD(hh, P, PH)                                              \
    do {                                                                     \
        const int _h = (hh);                                                 \
        if (_h >= 0 && _h < H) {                                             \
            const long long _r = colBase + (long long)_h * sH;               \
            P = *(const v4f*)(phi + _r);                                     \
            if (hasHalo) PH = *(const v4f*)(phi + _r + haloOff);             \
        }                                                                    \
    } while (0)

    // sincos of quad P -> SN/CS (kept), vector-store to LDS slot; halo too
    #define SINCOS_STORE(SLOT, P, PH, SN, CS)                                \
    do {                                                                     \
        const int _s = (SLOT);                                               \
        SN[0] = __sinf(P.x); SN[1] = __sinf(P.y);                            \
        SN[2] = __sinf(P.z); SN[3] = __sinf(P.w);                            \
        CS[0] = __cosf(P.x); CS[1] = __cosf(P.y);                            \
        CS[2] = __cosf(P.z); CS[3] = __cosf(P.w);                            \
        v4f _vs = {SN[0], SN[1], SN[2], SN[3]};                              \
        v4f _vc = {CS[0], CS[1], CS[2], CS[3]};                              \
        *(v4f*)&Ssin[_s][lwc][d0] = _vs;                                     \
        *(v4f*)&Scos[_s][lwc][d0] = _vc;                                     \
        if (hasHalo) {                                                       \
            v4f _hs = {__sinf(PH.x), __sinf(PH.y), __sinf(PH.z), __sinf(PH.w)}; \
            v4f _hc = {__cosf(PH.x), __cosf(PH.y), __cosf(PH.z), __cosf(PH.w)}; \
            *(v4f*)&Ssin[_s][haloLw][d0] = _hs;                              \
            *(v4f*)&Scos[_s][haloLw][d0] = _hc;                              \
        }                                                                    \
    } while (0)

    // lfs 6-value line (quad + d-halo scalars)
    #define LFS_LOAD(hh, F)                                                  \
    do {                                                                     \
        const int _h = (hh);                                                 \
        if (_h >= 0 && _h < H) {                                             \
            const long long _r = colBase + (long long)_h * sH;               \
            const v4f _l = *(const v4f*)(lfs + _r);                          \
            F[1] = _l.x; F[2] = _l.y; F[3] = _l.z; F[4] = _l.w;              \
            F[0] = (d0 > 0)     ? lfs[_r - 1] : 0.f;                         \
            F[5] = (d0 + 4 < D) ? lfs[_r + 4] : 0.f;                         \
        } else {                                                             \
            _Pragma("unroll")                                                \
            for (int _j = 0; _j < 6; ++_j) F[_j] = 0.f;                      \
        }                                                                    \
    } while (0)

    v4f pN  = {0.f, 0.f, 0.f, 0.f}, pNH  = {0.f, 0.f, 0.f, 0.f};
    float snC[4], csC[4], snT[4], csT[4];
    float FA[6], FB[6], FC[6];

    // prologue: row h0-1 -> slot 0; row h0 -> slot 1 (keep its sincos in regs)
    PHI_LOAD(h0 - 1, pN, pNH);
    SINCOS_STORE(0, pN, pNH, snT, csT);
    PHI_LOAD(h0, pN, pNH);
    SINCOS_STORE(1, pN, pNH, snC, csC);
    LFS_LOAD(h0 - 1, FA);
    LFS_LOAD(h0,     FB);
    PHI_LOAD(h0 + 1, pN, pNH);       // prefetched row h0+1

    int sm = 0, sc = 1, sp = 2;

    for (int i = 0; i < HS; ++i) {
        const int h = h0 + i;

        // row h+1: trans + aligned LDS writes; lfs line to ring
        SINCOS_STORE(sp, pN, pNH, snT, csT);
        LFS_LOAD(h + 1, FC);
        __syncthreads();

        // prefetch phi row h+2 under compute
        v4f pN2 = pN, pN2H = pNH;
        PHI_LOAD(h + 2, pN2, pN2H);

        const long long r = colBase + (long long)h * sH;
        if (h == 0 || h == H - 1 || w == 0 || w == W - 1) {
            const v4f z = {0.f, 0.f, 0.f, 0.f};
            __builtin_nontemporal_store(z, (v4f*)(out_b + r));
            __builtin_nontemporal_store(z, (v4f*)(out_d + r));
        } else {
            // aligned b128 LDS reads: w+/-1 (slot sc), h+/-1 (slots sm/sp)
            const v4f swm = *(const v4f*)&Ssin[sc][lwc - 1][d0];
            const v4f swp = *(const v4f*)&Ssin[sc][lwc + 1][d0];
            const v4f shm = *(const v4f*)&Ssin[sm][lwc][d0];
            const v4f shp = *(const v4f*)&Ssin[sp][lwc][d0];
            const v4f cwm = *(const v4f*)&Scos[sc][lwc - 1][d0];
            const v4f cwp = *(const v4f*)&Scos[sc][lwc + 1][d0];
            const v4f chm = *(const v4f*)&Scos[sm][lwc][d0];
            const v4f chp = *(const v4f*)&Scos[sp][lwc][d0];

            // d-edges from neighbor lanes (width-32 groups = same w-line)
            const float snL = __shfl_up(snC[3], 1, 32);
            const float snR = __shfl_down(snC[0], 1, 32);
            const float csL = __shfl_up(csC[3], 1, 32);
            const float csR = __shfl_down(csC[0], 1, 32);
            const float snx[6] = {snL, snC[0], snC[1], snC[2], snC[3], snR};
            const float csx[6] = {csL, csC[0], csC[1], csC[2], csC[3], csR};

            const v4f lw0 = *(const v4f*)(lfs + r - sW);
            const v4f lw1 = *(const v4f*)(lfs + r + sW);
            const v4f mk  = *(const v4f*)(mask + r);
            const float lwv0[4] = {lw0.x, lw0.y, lw0.z, lw0.w};
            const float lwv1[4] = {lw1.x, lw1.y, lw1.z, lw1.w};
            const float mkv[4]  = {mk.x, mk.y, mk.z, mk.w};
            const float swmv[4] = {swm.x, swm.y, swm.z, swm.w};
            const float swpv[4] = {swp.x, swp.y, swp.z, swp.w};
            const float shmv[4] = {shm.x, shm.y, shm.z, shm.w};
            const float shpv[4] = {shp.x, shp.y, shp.z, shp.w};
            const float cwmv[4] = {cwm.x, cwm.y, cwm.z, cwm.w};
            const float cwpv[4] = {cwp.x, cwp.y, cwp.z, cwp.w};
            const float chmv[4] = {chm.x, chm.y, chm.z, chm.w};
            const float chpv[4] = {chp.x, chp.y, chp.z, chp.w};

            float ob[4], od[4];
            #pragma unroll
            for (int j = 0; j < 4; ++j) {
                const float se = snx[j + 1], ce = csx[j + 1];
                const float a_r = kCc * ce
                    + kDc * (csx[j] + csx[j + 2])
                    + kWc * (cwmv[j] + cwpv[j])
                    + kHc * (chmv[j] + chpv[j]);
                const float a_i = kCc * se
                    + kDc * (snx[j] + snx[j + 2])
                    + kWc * (swmv[j] + swpv[j])
                    + kHc * (shmv[j] + shpv[j]);
                float bi = (a_i * ce - a_r * se) * mkv[j] * scale;

                const float lap = kCc * FB[j + 1]
                    + kDc * (FB[j] + FB[j + 2])
                    + kWc * (lwv0[j] + lwv1[j])
                    + kHc * (FA[j + 1] + FC[j + 1]);
                float dv = lap * mkv[j];

                const int d = d0 + j;
                if (d == 0 || d == D - 1) { bi = 0.f; dv = 0.f; }
                ob[j] = bi; od[j] = dv;
            }
            const v4f vb = {ob[0], ob[1], ob[2], ob[3]};
            const v4f vd = {od[0], od[1], od[2], od[3]};
            __builtin_nontemporal_store(vb, (v4f*)(out_b + r));
            __builtin_nontemporal_store(vd, (v4f*)(out_d + r));
        }

        // rotate register state + LDS ring
        #pragma unroll
        for (int j2 = 0; j2 < 4; ++j2) { snC[j2] = snT[j2]; csC[j2] = csT[j2]; }
        #pragma unroll
        for (int j2 = 0; j2 < 6; ++j2) { FA[j2] = FB[j2]; FB[j2] = FC[j2]; }
        pN = pN2; pNH = pN2H;
        const int t = sm; sm = sc; sc = sp; sp = t;

        __syncthreads();
    }

    #undef PHI_LOAD
    #undef SINCOS_STORE
    #undef LFS_LOAD
}

extern "C" void kernel_launch(void* const* d_in, const int* in_sizes, int n_in,
                              void* d_out, int out_size, void* d_ws, size_t ws_size,
                              hipStream_t stream) {
    const float* phi  = (const float*)d_in[0];
    const float* lfs  = (const float*)d_in[1];
    const float* mask = (const float*)d_in[2];
    const float* TE   = (const float*)d_in[3];
    const float* B0   = (const float*)d_in[4];
    const float* kern = (const float*)d_in[5];

    float* out_b = (float*)d_out;
    float* out_d = out_b + sB * 2;   // B=2, C=1

    dim3 grid(W / WT, H / HS, 2);
    dim3 block(256);
    hipLaunchKernelGGL(lot_lds_v2, grid, block, 0, stream,
                       phi, lfs, mask, TE, B0, kern, out_b, out_d);
}